// Round 6
// baseline (206.255 us; speedup 1.0000x reference)
//
#include <hip/hip_runtime.h>
#include <hip/hip_fp16.h>

// ---------------------------------------------------------------------------
// SoftDecisionTreeEnsemble: N_TREES=15, DEPTH=3, INPUT_DIM=128, N_CLASSES=10
// R4/R5: drop global_load_lds entirely. The LDS-DMA waitcnt pass loses the
// base object through addrspacecast+dynamic offsets -> conservative vmcnt(0)
// before ANY ds op -> R2/R3 pipeline never overlapped (tree_main ~40us).
// x is software-pipelined 2-deep in REGISTERS (P0/P1, 64 VGPR/thread):
// pure VMEM->VGPR deps get precise s_waitcnt vmcnt(8) from the compiler.
// LDS is only the 17KB wave-private postprocess scratch (no DMA -> no waits).
// R5 fix: 'half2' collided with hip_fp16.h's __half2 alias; cvt_pkrtz returns
// a native __fp16 x2 ext-vector -> use a distinct fp16x2 typedef.
// ---------------------------------------------------------------------------

typedef float    f32x4  __attribute__((ext_vector_type(4)));
typedef _Float16 half8  __attribute__((ext_vector_type(8)));
typedef __fp16   fp16x2 __attribute__((ext_vector_type(2)));

#define TREES      15
#define IDIM       128
#define NCLS       10
#define NINT       7
#define NLVS       8
#define PER_TREE   (NINT*IDIM + NINT + NLVS*NCLS)   // 983
#define NODES      (TREES*NINT)                     // 105
#define NPAD       112                              // 7 n-tiles of 16
#define KPAD       128                              // leaf K padded
#define RSTR       272                              // sigmoid/leaf row stride (bytes)
#define NBLK       512                              // 2 blocks/CU co-resident
#define TPB        8                                // 64-row tiles per block

// ---------------------------------------------------------------------------
// prep: wq[112][128] f16 (row g=7t+n, zero-padded), bq[112] f32 (zero-padded),
//       wbT[16][128] f16: wbT[c][8t+l] = softmax(leaf_logits[t][l])[c]*tw[t].
// Zero padding is load-bearing: pad nodes give z=0 -> sigmoid 0.5 (finite),
// Phase B masks tree-15's slot to 0, pad leaf cols multiply by 0.
// ---------------------------------------------------------------------------
__global__ __launch_bounds__(256) void prep_kernel(const float* __restrict__ p,
                                                   _Float16* __restrict__ wq,
                                                   float* __restrict__ bq,
                                                   _Float16* __restrict__ wbT) {
    const int gid  = blockIdx.x * 256 + threadIdx.x;
    const int nthr = gridDim.x * 256;

    for (int i = gid; i < NPAD * IDIM; i += nthr) {
        int g = i >> 7, k = i & 127;
        float v = 0.f;
        if (g < NODES) {
            int t = g / NINT, n = g % NINT;
            v = p[t * PER_TREE + n * IDIM + k];
        }
        wq[i] = (_Float16)v;
    }
    for (int i = gid; i < NPAD; i += nthr) {
        float v = 0.f;
        if (i < NODES) {
            int t = i / NINT, n = i % NINT;
            v = p[t * PER_TREE + NINT * IDIM + n];
        }
        bq[i] = v;
    }
    const float* tl = p + TREES * PER_TREE;
    for (int i = gid; i < 16 * KPAD; i += nthr) {
        int c = i >> 7, k = i & 127;
        float v = 0.f;
        if (c < NCLS && k < TREES * NLVS) {
            int t = k >> 3, l = k & 7;
            const float* ll = p + t * PER_TREE + NINT * IDIM + NINT + l * NCLS;
            float mx = ll[0];
            #pragma unroll
            for (int j = 1; j < NCLS; ++j) mx = fmaxf(mx, ll[j]);
            float se = 0.f;
            #pragma unroll
            for (int j = 0; j < NCLS; ++j) se += __expf(ll[j] - mx);
            float lsm = __expf(ll[c] - mx) / se;

            float m2 = tl[0];
            #pragma unroll
            for (int j = 1; j < TREES; ++j) m2 = fmaxf(m2, tl[j]);
            float s2 = 0.f;
            #pragma unroll
            for (int j = 0; j < TREES; ++j) s2 += __expf(tl[j] - m2);
            float tw = __expf(tl[t] - m2) / s2;
            v = lsm * tw;
        }
        wbT[i] = (_Float16)v;
    }
}

// ---------------------------------------------------------------------------
__global__ __launch_bounds__(256, 2) void tree_main(const float* __restrict__ x,
                                                    const _Float16* __restrict__ wq,
                                                    const float* __restrict__ bq,
                                                    const _Float16* __restrict__ wbT,
                                                    float* __restrict__ out) {
    __shared__ __align__(16) char lds[4][16 * RSTR];   // wave-private scratch

    const int tid  = threadIdx.x;
    const int lane = tid & 63;
    const int w    = tid >> 6;        // wave id: owns rows 16w..16w+15 of tile
    const int lm   = lane & 15;
    const int lq   = lane >> 4;
    const int rg   = lane >> 2;       // Phase B row (0..15)
    const int g    = lane & 3;        // Phase B tree group

    char* q = &lds[w][0];

    const long tile0 = (long)blockIdx.x * TPB;

    // resident weights (compiler may remat from L1-hot wq; acceptable)
    half8 bf[7][4];
    float bb[7];
    #pragma unroll
    for (int nt = 0; nt < 7; ++nt) {
        bb[nt] = bq[16 * nt + lm];
        #pragma unroll
        for (int s = 0; s < 4; ++s)
            bf[nt][s] = *reinterpret_cast<const half8*>(wq + (16 * nt + lm) * IDIM + 32 * s + 8 * lq);
    }
    half8 wbf[4];
    #pragma unroll
    for (int s = 0; s < 4; ++s)
        wbf[s] = *reinterpret_cast<const half8*>(wbT + lm * KPAD + 32 * s + 8 * lq);

    // x prefetch: thread covers row (tile*64 + 16w + lm), floats [8lq+32s, +8)
    f32x4 P0[8], P1[8];
    auto ldx = [&](f32x4 P[8], long tile) {
        const float* xr = x + ((tile << 6) + 16 * w + lm) * IDIM + 8 * lq;
        #pragma unroll
        for (int s = 0; s < 4; ++s) {
            P[2 * s]     = *reinterpret_cast<const f32x4*>(xr + 32 * s);
            P[2 * s + 1] = *reinterpret_cast<const f32x4*>(xr + 32 * s + 4);
        }
    };

    // f32 prefetch regs -> f16 A-fragments (packed cvt, RTZ)
    auto cvt = [&](const f32x4 P[8], half8 af[4]) {
        #pragma unroll
        for (int s = 0; s < 4; ++s) {
            fp16x2 h0 = __builtin_amdgcn_cvt_pkrtz(P[2*s][0],   P[2*s][1]);
            fp16x2 h1 = __builtin_amdgcn_cvt_pkrtz(P[2*s][2],   P[2*s][3]);
            fp16x2 h2 = __builtin_amdgcn_cvt_pkrtz(P[2*s+1][0], P[2*s+1][1]);
            fp16x2 h3 = __builtin_amdgcn_cvt_pkrtz(P[2*s+1][2], P[2*s+1][3]);
            half8 a;
            a[0] = (_Float16)h0[0]; a[1] = (_Float16)h0[1];
            a[2] = (_Float16)h1[0]; a[3] = (_Float16)h1[1];
            a[4] = (_Float16)h2[0]; a[5] = (_Float16)h2[1];
            a[6] = (_Float16)h3[0]; a[7] = (_Float16)h3[1];
            af[s] = a;
        }
    };

    auto compute = [&](const half8 af[4], long tile) {
        // ---- Phase A: z-GEMM + sigmoid -> packed cols 8t+n ----
        #pragma unroll
        for (int nt = 0; nt < 7; ++nt) {
            f32x4 acc = {0.f, 0.f, 0.f, 0.f};
            #pragma unroll
            for (int s = 0; s < 4; ++s)
                acc = __builtin_amdgcn_mfma_f32_16x16x32_f16(af[s], bf[nt][s], acc, 0, 0, 0);
            int node = 16 * nt + lm;
            int col  = node + ((node * 9363) >> 16);   // node + node/7 = 8t+n
            #pragma unroll
            for (int r = 0; r < 4; ++r) {
                float z  = acc[r] + bb[nt];            // C/D: row=4lq+r, col=lm
                float sg = __builtin_amdgcn_rcpf(1.0f + __expf(-z));
                *(_Float16*)(q + (4 * lq + r) * RSTR + col * 2) = (_Float16)sg;
            }
        }

        // ---- Phase B: leaf probabilities (wave-lockstep, reads before writes) ----
        {
            const char* rowp = q + rg * RSTR;
            half8 sv[4];
            #pragma unroll
            for (int tt = 0; tt < 4; ++tt)
                sv[tt] = *(const half8*)(rowp + (8 * (4 * g + tt)) * 2);  // n=0..6 (+1 pad)
            half8 lv[4];
            #pragma unroll
            for (int tt = 0; tt < 4; ++tt) {
                float s0 = (float)sv[tt][0], s1 = (float)sv[tt][1], s2 = (float)sv[tt][2];
                float s3 = (float)sv[tt][3], s4 = (float)sv[tt][4], s5 = (float)sv[tt][5];
                float s6 = (float)sv[tt][6];
                float u1 = 1.f - s0, u2 = s0;
                float q1 = u1 * s1, q0 = u1 - q1;
                float q3 = u2 * s2, q2 = u2 - q3;
                float L1 = q0 * s3, L0 = q0 - L1;
                float L3 = q1 * s4, L2 = q1 - L3;
                float L5 = q2 * s5, L4 = q2 - L5;
                float L7 = q3 * s6, L6 = q3 - L7;
                float m = (4 * g + tt < TREES) ? 1.f : 0.f;   // zero tree-15 slot
                half8 lv8;
                lv8[0] = (_Float16)(L0 * m); lv8[1] = (_Float16)(L1 * m);
                lv8[2] = (_Float16)(L2 * m); lv8[3] = (_Float16)(L3 * m);
                lv8[4] = (_Float16)(L4 * m); lv8[5] = (_Float16)(L5 * m);
                lv8[6] = (_Float16)(L6 * m); lv8[7] = (_Float16)(L7 * m);
                lv[tt] = lv8;
            }
            #pragma unroll
            for (int tt = 0; tt < 4; ++tt)
                *(half8*)(q + rg * RSTR + 64 * g + 16 * tt) = lv[tt];
        }

        // ---- Phase C: leaf x wbT MFMA -> out ----
        {
            half8 af2[4];
            #pragma unroll
            for (int s = 0; s < 4; ++s)
                af2[s] = *(const half8*)(q + lm * RSTR + 64 * s + 16 * lq);
            f32x4 a2 = {0.f, 0.f, 0.f, 0.f};
            #pragma unroll
            for (int s = 0; s < 4; ++s)
                a2 = __builtin_amdgcn_mfma_f32_16x16x32_f16(af2[s], wbf[s], a2, 0, 0, 0);
            if (lm < NCLS) {
                const long grow = (tile << 6) + 16 * w;
                #pragma unroll
                for (int r = 0; r < 4; ++r)
                    out[(grow + 4 * lq + r) * NCLS + lm] = a2[r];
            }
        }
    };

    // 2-deep register pipeline; TPB even.
    ldx(P0, tile0 + 0);
    ldx(P1, tile0 + 1);
    for (int i = 0; i < TPB; i += 2) {
        half8 af[4];
        cvt(P0, af);                               // waits vmcnt(8): P1 stays in flight
        if (i + 2 < TPB) ldx(P0, tile0 + i + 2);   // refill after WAR clears
        compute(af, tile0 + i);
        cvt(P1, af);
        if (i + 3 < TPB) ldx(P1, tile0 + i + 3);
        compute(af, tile0 + i + 1);
    }
}

// ---------------------------------------------------------------------------
extern "C" void kernel_launch(void* const* d_in, const int* in_sizes, int n_in,
                              void* d_out, int out_size, void* d_ws, size_t ws_size,
                              hipStream_t stream) {
    const float* x      = (const float*)d_in[0];
    const float* params = (const float*)d_in[1];
    float* out = (float*)d_out;

    _Float16* wq  = (_Float16*)d_ws;                             // 28672 B
    float*    bq  = (float*)((char*)d_ws + NPAD * IDIM * 2);     // 448 B
    _Float16* wbT = (_Float16*)((char*)bq + NPAD * 4);           // 4096 B

    prep_kernel<<<8, 256, 0, stream>>>(params, wq, bq, wbT);
    tree_main<<<NBLK, 256, 0, stream>>>(x, wq, bq, wbT, out);
}

// Round 7
// 205.278 us; speedup vs baseline: 1.0048x; 1.0048x over previous
//
#include <hip/hip_runtime.h>
#include <hip/hip_fp16.h>

// ---------------------------------------------------------------------------
// SoftDecisionTreeEnsemble: N_TREES=15, DEPTH=3, INPUT_DIM=128, N_CLASSES=10
// R6: kill the REAL serializer. R2-R5 all plateaued at tree_main ~65us because
// the 112-VGPR B-fragment array was never kept resident: the compiler remats
// 28 global loads of wq per tile, their s_waitcnt retires vmcnt IN ORDER ->
// every tile waits for all older in-flight x loads -> pipeline drained no
// matter how x is delivered (LDS-DMA or register prefetch).
// Fix: stage wq/wbT/bq in LDS once per block (272B row stride, conflict-free);
// in-loop weight reads become ds_read_b128 (lgkmcnt, NOT vmcnt). The vmcnt
// stream is now x loads + out stores only; P0/P1 register pipeline (64 VGPR,
// total ~130 -> no spills) gets precise vmcnt(8) overlap.
// ---------------------------------------------------------------------------

typedef float    f32x4  __attribute__((ext_vector_type(4)));
typedef _Float16 half8  __attribute__((ext_vector_type(8)));
typedef __fp16   fp16x2 __attribute__((ext_vector_type(2)));

#define TREES      15
#define IDIM       128
#define NCLS       10
#define NINT       7
#define NLVS       8
#define PER_TREE   (NINT*IDIM + NINT + NLVS*NCLS)   // 983
#define NODES      (TREES*NINT)                     // 105
#define NPAD       112                              // 7 n-tiles of 16
#define KPAD       128                              // leaf K padded
#define RSTR       272                              // scratch row stride (bytes)
#define WSTR       272                              // staged weight row stride (bytes)
#define NBLK       512                              // 2 blocks/CU co-resident
#define TPB        8                                // 64-row tiles per block

// ---------------------------------------------------------------------------
// prep: wq[112][128] f16 (row g=7t+n, zero-padded), bq[112] f32 (zero-padded),
//       wbT[16][128] f16: wbT[c][8t+l] = softmax(leaf_logits[t][l])[c]*tw[t].
// Zero padding is load-bearing: pad nodes give z=0 -> sigmoid 0.5 (finite),
// Phase B masks tree-15's slot to 0, pad leaf cols multiply by 0.
// ---------------------------------------------------------------------------
__global__ __launch_bounds__(256) void prep_kernel(const float* __restrict__ p,
                                                   _Float16* __restrict__ wq,
                                                   float* __restrict__ bq,
                                                   _Float16* __restrict__ wbT) {
    const int gid  = blockIdx.x * 256 + threadIdx.x;
    const int nthr = gridDim.x * 256;

    for (int i = gid; i < NPAD * IDIM; i += nthr) {
        int g = i >> 7, k = i & 127;
        float v = 0.f;
        if (g < NODES) {
            int t = g / NINT, n = g % NINT;
            v = p[t * PER_TREE + n * IDIM + k];
        }
        wq[i] = (_Float16)v;
    }
    for (int i = gid; i < NPAD; i += nthr) {
        float v = 0.f;
        if (i < NODES) {
            int t = i / NINT, n = i % NINT;
            v = p[t * PER_TREE + NINT * IDIM + n];
        }
        bq[i] = v;
    }
    const float* tl = p + TREES * PER_TREE;
    for (int i = gid; i < 16 * KPAD; i += nthr) {
        int c = i >> 7, k = i & 127;
        float v = 0.f;
        if (c < NCLS && k < TREES * NLVS) {
            int t = k >> 3, l = k & 7;
            const float* ll = p + t * PER_TREE + NINT * IDIM + NINT + l * NCLS;
            float mx = ll[0];
            #pragma unroll
            for (int j = 1; j < NCLS; ++j) mx = fmaxf(mx, ll[j]);
            float se = 0.f;
            #pragma unroll
            for (int j = 0; j < NCLS; ++j) se += __expf(ll[j] - mx);
            float lsm = __expf(ll[c] - mx) / se;

            float m2 = tl[0];
            #pragma unroll
            for (int j = 1; j < TREES; ++j) m2 = fmaxf(m2, tl[j]);
            float s2 = 0.f;
            #pragma unroll
            for (int j = 0; j < TREES; ++j) s2 += __expf(tl[j] - m2);
            float tw = __expf(tl[t] - m2) / s2;
            v = lsm * tw;
        }
        wbT[i] = (_Float16)v;
    }
}

// ---------------------------------------------------------------------------
__global__ __launch_bounds__(256, 2) void tree_main(const float* __restrict__ x,
                                                    const _Float16* __restrict__ wq,
                                                    const float* __restrict__ bq,
                                                    const _Float16* __restrict__ wbT,
                                                    float* __restrict__ out) {
    // Staged weights: 272B row stride -> ds_read_b128 by (lm,lq) lands on
    // distinct bank pairs (4*lm mod 32: 2-way aliasing = free).
    __shared__ __align__(16) char  wqs[NPAD * WSTR];     // 30464 B
    __shared__ __align__(16) char  wbs[16 * WSTR];       //  4352 B
    __shared__ __align__(16) float bqs[NPAD];            //   448 B
    __shared__ __align__(16) char  scr[4][16 * RSTR];    // 17408 B  (wave scratch)

    const int tid  = threadIdx.x;
    const int lane = tid & 63;
    const int w    = tid >> 6;        // wave id: owns rows 16w..16w+15 of tile
    const int lm   = lane & 15;
    const int lq   = lane >> 4;
    const int rg   = lane >> 2;       // Phase B row (0..15)
    const int g    = lane & 3;        // Phase B tree group

    char* q = &scr[w][0];

    // ---- stage weights global -> LDS (once per block) ----
    for (int i = tid; i < NPAD * 16; i += 256) {         // 16B chunks
        int r = i >> 4, c = i & 15;
        *(f32x4*)(wqs + r * WSTR + c * 16) =
            *(const f32x4*)((const char*)wq + r * 256 + c * 16);
    }
    {
        int r = tid >> 4, c = tid & 15;                  // 256 chunks exactly
        *(f32x4*)(wbs + r * WSTR + c * 16) =
            *(const f32x4*)((const char*)wbT + r * 256 + c * 16);
    }
    if (tid < NPAD) bqs[tid] = bq[tid];
    __syncthreads();

    const long tile0 = (long)blockIdx.x * TPB;

    // x prefetch: thread covers row (tile*64 + 16w + lm), floats [8lq+32s, +8)
    f32x4 P0[8], P1[8];
    auto ldx = [&](f32x4 P[8], long tile) {
        const float* xr = x + ((tile << 6) + 16 * w + lm) * IDIM + 8 * lq;
        #pragma unroll
        for (int s = 0; s < 4; ++s) {
            P[2 * s]     = *reinterpret_cast<const f32x4*>(xr + 32 * s);
            P[2 * s + 1] = *reinterpret_cast<const f32x4*>(xr + 32 * s + 4);
        }
    };

    // f32 prefetch regs -> f16 A-fragments (packed cvt, RTZ)
    auto cvt = [&](const f32x4 P[8], half8 af[4]) {
        #pragma unroll
        for (int s = 0; s < 4; ++s) {
            fp16x2 h0 = __builtin_amdgcn_cvt_pkrtz(P[2*s][0],   P[2*s][1]);
            fp16x2 h1 = __builtin_amdgcn_cvt_pkrtz(P[2*s][2],   P[2*s][3]);
            fp16x2 h2 = __builtin_amdgcn_cvt_pkrtz(P[2*s+1][0], P[2*s+1][1]);
            fp16x2 h3 = __builtin_amdgcn_cvt_pkrtz(P[2*s+1][2], P[2*s+1][3]);
            half8 a;
            a[0] = (_Float16)h0[0]; a[1] = (_Float16)h0[1];
            a[2] = (_Float16)h1[0]; a[3] = (_Float16)h1[1];
            a[4] = (_Float16)h2[0]; a[5] = (_Float16)h2[1];
            a[6] = (_Float16)h3[0]; a[7] = (_Float16)h3[1];
            af[s] = a;
        }
    };

    auto compute = [&](const half8 af[4], long tile) {
        // ---- Phase A: z-GEMM (B-frags from LDS) + sigmoid -> cols 8t+n ----
        #pragma unroll
        for (int nt = 0; nt < 7; ++nt) {
            f32x4 acc = {0.f, 0.f, 0.f, 0.f};
            #pragma unroll
            for (int s = 0; s < 4; ++s) {
                half8 bfr = *(const half8*)(wqs + (16 * nt + lm) * WSTR + 64 * s + 16 * lq);
                acc = __builtin_amdgcn_mfma_f32_16x16x32_f16(af[s], bfr, acc, 0, 0, 0);
            }
            float bbn = bqs[16 * nt + lm];
            int node = 16 * nt + lm;
            int col  = node + ((node * 9363) >> 16);   // node + node/7 = 8t+n
            #pragma unroll
            for (int r = 0; r < 4; ++r) {
                float z  = acc[r] + bbn;               // C/D: row=4lq+r, col=lm
                float sg = __builtin_amdgcn_rcpf(1.0f + __expf(-z));
                *(_Float16*)(q + (4 * lq + r) * RSTR + col * 2) = (_Float16)sg;
            }
        }

        // ---- Phase B: leaf probabilities (wave-lockstep, reads before writes) ----
        {
            const char* rowp = q + rg * RSTR;
            half8 sv[4];
            #pragma unroll
            for (int tt = 0; tt < 4; ++tt)
                sv[tt] = *(const half8*)(rowp + (8 * (4 * g + tt)) * 2);  // n=0..6 (+1 pad)
            half8 lv[4];
            #pragma unroll
            for (int tt = 0; tt < 4; ++tt) {
                float s0 = (float)sv[tt][0], s1 = (float)sv[tt][1], s2 = (float)sv[tt][2];
                float s3 = (float)sv[tt][3], s4 = (float)sv[tt][4], s5 = (float)sv[tt][5];
                float s6 = (float)sv[tt][6];
                float u1 = 1.f - s0, u2 = s0;
                float q1 = u1 * s1, q0 = u1 - q1;
                float q3 = u2 * s2, q2 = u2 - q3;
                float L1 = q0 * s3, L0 = q0 - L1;
                float L3 = q1 * s4, L2 = q1 - L3;
                float L5 = q2 * s5, L4 = q2 - L5;
                float L7 = q3 * s6, L6 = q3 - L7;
                float m = (4 * g + tt < TREES) ? 1.f : 0.f;   // zero tree-15 slot
                half8 lv8;
                lv8[0] = (_Float16)(L0 * m); lv8[1] = (_Float16)(L1 * m);
                lv8[2] = (_Float16)(L2 * m); lv8[3] = (_Float16)(L3 * m);
                lv8[4] = (_Float16)(L4 * m); lv8[5] = (_Float16)(L5 * m);
                lv8[6] = (_Float16)(L6 * m); lv8[7] = (_Float16)(L7 * m);
                lv[tt] = lv8;
            }
            #pragma unroll
            for (int tt = 0; tt < 4; ++tt)
                *(half8*)(q + rg * RSTR + 64 * g + 16 * tt) = lv[tt];
        }

        // ---- Phase C: leaf x wbT MFMA (B-frags from LDS) -> out ----
        {
            f32x4 a2 = {0.f, 0.f, 0.f, 0.f};
            #pragma unroll
            for (int s = 0; s < 4; ++s) {
                half8 af2 = *(const half8*)(q + lm * RSTR + 64 * s + 16 * lq);
                half8 wbf = *(const half8*)(wbs + lm * WSTR + 64 * s + 16 * lq);
                a2 = __builtin_amdgcn_mfma_f32_16x16x32_f16(af2, wbf, a2, 0, 0, 0);
            }
            if (lm < NCLS) {
                const long grow = (tile << 6) + 16 * w;
                #pragma unroll
                for (int r = 0; r < 4; ++r)
                    out[(grow + 4 * lq + r) * NCLS + lm] = a2[r];
            }
        }
    };

    // 2-deep register pipeline; TPB even.
    ldx(P0, tile0 + 0);
    ldx(P1, tile0 + 1);
    for (int i = 0; i < TPB; i += 2) {
        half8 af[4];
        cvt(P0, af);                               // waits vmcnt(8): P1 stays in flight
        if (i + 2 < TPB) ldx(P0, tile0 + i + 2);   // refill after WAR clears
        compute(af, tile0 + i);
        cvt(P1, af);
        if (i + 3 < TPB) ldx(P1, tile0 + i + 3);
        compute(af, tile0 + i + 1);
    }
}

// ---------------------------------------------------------------------------
extern "C" void kernel_launch(void* const* d_in, const int* in_sizes, int n_in,
                              void* d_out, int out_size, void* d_ws, size_t ws_size,
                              hipStream_t stream) {
    const float* x      = (const float*)d_in[0];
    const float* params = (const float*)d_in[1];
    float* out = (float*)d_out;

    _Float16* wq  = (_Float16*)d_ws;                             // 28672 B
    float*    bq  = (float*)((char*)d_ws + NPAD * IDIM * 2);     // 448 B
    _Float16* wbT = (_Float16*)((char*)bq + NPAD * 4);           // 4096 B

    prep_kernel<<<8, 256, 0, stream>>>(params, wq, bq, wbT);
    tree_main<<<NBLK, 256, 0, stream>>>(x, wq, bq, wbT, out);
}